// Round 1
// baseline (298.038 us; speedup 1.0000x reference)
//
#include <hip/hip_runtime.h>

// out[b,d,t] = sum_c x[b,c,t] * weights[subjects[b],c,d]
// B=256, C=270, T=1024, NSUB=200. fp32 in/out, bf16 MFMA internally.

#define C_    270
#define T_    1024
#define B_    256
#define NSUB_ 200

#define BM 96      // d-tile
#define BN 128     // t-tile
#define BK 32      // c-step
#define NK 9       // ceil(270/32) -> K padded to 288
#define ROWU32 20  // u32 per LDS row: 16 used (32 bf16) + 4 pad (16B-aligned rows)

typedef __attribute__((ext_vector_type(8))) short bf16x8;
typedef __attribute__((ext_vector_type(4))) float f32x4;
typedef __attribute__((ext_vector_type(2))) float f32x2;

__device__ __forceinline__ unsigned pack_bf16x2(float lo, float hi) {
    // round-to-nearest-even f32 -> bf16, packed (lo in low 16 bits)
    unsigned a = __builtin_bit_cast(unsigned, lo);
    unsigned b = __builtin_bit_cast(unsigned, hi);
    a += 0x7FFFu + ((a >> 16) & 1u);
    b += 0x7FFFu + ((b >> 16) & 1u);
    return (a >> 16) | (b & 0xFFFF0000u);
}

// 16-byte-block XOR swizzle: permutes u32-column bits [3:2] by row bits [4:3].
// Applied identically on write and read -> data exact; breaks bank aliasing.
__device__ __forceinline__ int swz_col(int row, int c2) {
    return (c2 & 3) | ((((c2 >> 2) ^ ((row >> 3) & 3)) & 3) << 2);
}

__global__ __launch_bounds__(256)
void subj_layers_kernel(const float* __restrict__ x,
                        const int* __restrict__ subjects,
                        const float* __restrict__ w,
                        float* __restrict__ out)
{
    __shared__ unsigned A32[BM * ROWU32];  // A tile: [96 d][32 c] bf16, k-contiguous
    __shared__ unsigned B32[BN * ROWU32];  // B tile: [128 t][32 c] bf16, k-contiguous

    const int tid  = threadIdx.x;
    const int lane = tid & 63;
    const int wid  = tid >> 6;
    const int wr   = wid >> 1;   // wave row (d): 0..1
    const int wc   = wid & 1;    // wave col (t): 0..1
    const int lg   = lane >> 4;  // 16-lane group 0..3
    const int lr   = lane & 15;

    const int bid = blockIdx.x;
    const int b   = bid / 24;
    const int rem = bid % 24;
    const int d0  = (rem >> 3) * BM;  // 0,96,192
    const int t0  = (rem & 7) * BN;   // 0..896

    int sub = subjects[b];
    sub = sub < 0 ? 0 : (sub >= NSUB_ ? NSUB_ - 1 : sub);
    const float* __restrict__ wsub = w + (size_t)sub * (C_ * C_);
    const float* __restrict__ xb   = x + (size_t)b * (C_ * T_);

    f32x4 acc[3][4];
    #pragma unroll
    for (int m = 0; m < 3; ++m)
        #pragma unroll
        for (int n = 0; n < 4; ++n)
            acc[m][n] = (f32x4){0.f, 0.f, 0.f, 0.f};

    const int c2t = tid >> 4;   // 0..15: which c-pair column this thread stages
    const int pl  = tid & 15;   // 0..15: row-pair lane within staging

    for (int kk = 0; kk < NK; ++kk) {
        const int c0  = kk * BK;
        const int c   = c0 + c2t * 2;
        const bool cok = (c < C_);  // c even, 270 even -> pair fully in/out

        // ---- stage A: weights^T tile. global rows are c (d-contiguous) ----
        #pragma unroll
        for (int i = 0; i < 3; ++i) {
            const int dp = pl + 16 * i;        // d-pair index 0..47
            const int d  = d0 + dp * 2;
            float a0 = 0.f, a1 = 0.f, b0v = 0.f, b1v = 0.f;
            if (cok && d < C_) {
                f32x2 va = *(const f32x2*)(wsub + (size_t)c * C_ + d);
                f32x2 vb = *(const f32x2*)(wsub + (size_t)(c + 1) * C_ + d);
                a0 = va.x; a1 = va.y; b0v = vb.x; b1v = vb.y;
            }
            const int r0 = dp * 2;
            A32[r0 * ROWU32 + swz_col(r0, c2t)]           = pack_bf16x2(a0, b0v);
            A32[(r0 + 1) * ROWU32 + swz_col(r0 + 1, c2t)] = pack_bf16x2(a1, b1v);
        }

        // ---- stage B: x tile. global rows are c (t-contiguous) ----
        #pragma unroll
        for (int i = 0; i < 4; ++i) {
            const int tp = pl + 16 * i;        // t-pair index 0..63
            const int t  = t0 + tp * 2;
            float a0 = 0.f, a1 = 0.f, b0v = 0.f, b1v = 0.f;
            if (cok) {
                f32x2 va = *(const f32x2*)(xb + (size_t)c * T_ + t);
                f32x2 vb = *(const f32x2*)(xb + (size_t)(c + 1) * T_ + t);
                a0 = va.x; a1 = va.y; b0v = vb.x; b1v = vb.y;
            }
            const int r0 = tp * 2;
            B32[r0 * ROWU32 + swz_col(r0, c2t)]           = pack_bf16x2(a0, b0v);
            B32[(r0 + 1) * ROWU32 + swz_col(r0 + 1, c2t)] = pack_bf16x2(a1, b1v);
        }

        __syncthreads();

        // ---- fragments + MFMA ----
        bf16x8 af[3], bfr[4];
        #pragma unroll
        for (int m = 0; m < 3; ++m) {
            const int row = wr * 48 + m * 16 + lr;
            af[m] = *(const bf16x8*)(A32 + row * ROWU32 + ((lg ^ ((row >> 3) & 3)) << 2));
        }
        #pragma unroll
        for (int n = 0; n < 4; ++n) {
            const int row = wc * 64 + n * 16 + lr;
            bfr[n] = *(const bf16x8*)(B32 + row * ROWU32 + ((lg ^ ((row >> 3) & 3)) << 2));
        }
        #pragma unroll
        for (int m = 0; m < 3; ++m)
            #pragma unroll
            for (int n = 0; n < 4; ++n)
                acc[m][n] = __builtin_amdgcn_mfma_f32_16x16x32_bf16(af[m], bfr[n], acc[m][n], 0, 0, 0);

        __syncthreads();
    }

    // ---- epilogue: C/D layout col=lane&15, row=(lane>>4)*4+reg ----
    float* outb = out + (size_t)b * (C_ * T_);
    #pragma unroll
    for (int m = 0; m < 3; ++m) {
        const int dbase = d0 + wr * 48 + m * 16 + 4 * lg;
        #pragma unroll
        for (int n = 0; n < 4; ++n) {
            const int t = t0 + wc * 64 + n * 16 + lr;
            #pragma unroll
            for (int rr = 0; rr < 4; ++rr) {
                const int d = dbase + rr;
                if (d < C_)
                    outb[(size_t)d * T_ + t] = acc[m][n][rr];
            }
        }
    }
}

extern "C" void kernel_launch(void* const* d_in, const int* in_sizes, int n_in,
                              void* d_out, int out_size, void* d_ws, size_t ws_size,
                              hipStream_t stream)
{
    const float* x        = (const float*)d_in[0];
    const int*   subjects = (const int*)d_in[1];
    const float* w        = (const float*)d_in[2];
    float* out            = (float*)d_out;

    dim3 grid(B_ * 24);  // 256 batches * (3 d-tiles * 8 t-tiles)
    dim3 block(256);
    hipLaunchKernelGGL(subj_layers_kernel, grid, block, 0, stream,
                       x, subjects, w, out);
}

// Round 3
// 210.616 us; speedup vs baseline: 1.4151x; 1.4151x over previous
//
#include <hip/hip_runtime.h>

// out[b,d,t] = sum_c x[b,c,t] * weights[subjects[b],c,d]
// B=256, C=270, T=1024, NSUB=200. fp32 in/out, bf16 MFMA internally.
// Pipeline: double-buffered LDS, register prefetch of K-step k+1 issued
// before compute of step k (T14), 1 barrier per K-step.

#define C_    270
#define T_    1024
#define B_    256
#define NSUB_ 200

#define BM 96      // d-tile
#define BN 128     // t-tile
#define BK 32      // c-step
#define NK 9       // K padded 270 -> 288
#define ROWU32 20  // u32 per LDS row: 16 used (32 bf16) + 4 pad
#define BOFF (BM * ROWU32)
#define LDSU32 ((BM + BN) * ROWU32)

typedef __attribute__((ext_vector_type(8))) short bf16x8;
typedef __attribute__((ext_vector_type(4))) float f32x4;
typedef __attribute__((ext_vector_type(2))) float f32x2;
typedef __attribute__((ext_vector_type(2))) unsigned u32x2;

__device__ __forceinline__ unsigned pk(float lo, float hi) {
    // round-to-nearest-even f32 -> bf16, packed (lo in low 16 bits)
    unsigned a = __builtin_bit_cast(unsigned, lo);
    unsigned b = __builtin_bit_cast(unsigned, hi);
    a += 0x7FFFu + ((a >> 16) & 1u);
    b += 0x7FFFu + ((b >> 16) & 1u);
    return (a >> 16) | (b & 0xFFFF0000u);
}

// 16-byte-block XOR swizzle on u32 columns: bits[3:2] ^= row bits[4:3].
// Keeps bits[1:0] -> b64 pair and b128 quad adjacency preserved.
__device__ __forceinline__ int swz_col(int row, int c2) {
    return (c2 & 3) | ((((c2 >> 2) ^ ((row >> 3) & 3)) & 3) << 2);
}

__global__ __launch_bounds__(256, 4)
void subj_layers_kernel(const float* __restrict__ x,
                        const int* __restrict__ subjects,
                        const float* __restrict__ w,
                        float* __restrict__ out)
{
    __shared__ unsigned lds[2][LDSU32];

    const int tid  = threadIdx.x;
    const int lane = tid & 63;
    const int wid  = tid >> 6;
    const int wr   = wid >> 1;   // wave d-row 0..1
    const int wc   = wid & 1;    // wave t-col 0..1
    const int lg   = lane >> 4;
    const int lr   = lane & 15;

    const int bid = blockIdx.x;
    const int b   = bid / 24;
    const int rem = bid % 24;
    const int d0  = (rem >> 3) * BM;  // 0,96,192
    const int t0  = (rem & 7) * BN;   // 0..896

    int sub = subjects[b];
    sub = sub < 0 ? 0 : (sub >= NSUB_ ? NSUB_ - 1 : sub);
    const float* __restrict__ wsub = w + (size_t)sub * (C_ * C_);
    const float* __restrict__ xb   = x + (size_t)b * (C_ * T_);

    // ---- staging decomposition ----
    // B (x) : 256 items, 1/thread. item = (t-quad, c-quad): 4x float4 loads, 4x b64 writes
    const int btq = tid & 31;          // t-quad 0..31
    const int bcq = tid >> 5;          // c-quad 0..7
    const int tB  = t0 + 4 * btq;
    const float* __restrict__ xbt = xb + tB;
    // A (w) : 384 items (48 d-pairs x 8 c-quads), 1.5/thread: 4x f32x2 loads, 2x b64 writes each
    const int adp0 = tid % 48,        acq0 = tid / 48;
    const int adp1 = (256 + tid) % 48, acq1 = (256 + tid) / 48;
    const bool hasA1 = (tid < 128);
    const int dA0 = d0 + 2 * adp0;  const bool dA0ok = (dA0 + 1 < C_);
    const int dA1 = d0 + 2 * adp1;  const bool dA1ok = (dA1 + 1 < C_);

    f32x4 acc[3][4];
    #pragma unroll
    for (int m = 0; m < 3; ++m)
        #pragma unroll
        for (int n = 0; n < 4; ++n)
            acc[m][n] = (f32x4){0.f, 0.f, 0.f, 0.f};

    auto load_tiles = [&](int c0, f32x4 pb[4], f32x2 pa0[4], f32x2 pa1[4]) {
        #pragma unroll
        for (int e = 0; e < 4; ++e) {
            const int c = c0 + 4 * bcq + e;
            pb[e] = (c < C_) ? *(const f32x4*)(xbt + (size_t)c * T_)
                             : (f32x4){0.f, 0.f, 0.f, 0.f};
        }
        #pragma unroll
        for (int e = 0; e < 4; ++e) {
            const int c = c0 + 4 * acq0 + e;
            pa0[e] = (dA0ok && c < C_) ? *(const f32x2*)(wsub + (size_t)c * C_ + dA0)
                                       : (f32x2){0.f, 0.f};
        }
        #pragma unroll
        for (int e = 0; e < 4; ++e) {
            const int c = c0 + 4 * acq1 + e;
            pa1[e] = (hasA1 && dA1ok && c < C_) ? *(const f32x2*)(wsub + (size_t)c * C_ + dA1)
                                                : (f32x2){0.f, 0.f};
        }
    };

    auto store_tiles = [&](unsigned* L, const f32x4 pb[4], const f32x2 pa0[4], const f32x2 pa1[4]) {
        unsigned* LB = L + BOFF;
        #pragma unroll
        for (int j = 0; j < 4; ++j) {
            const int r = 4 * btq + j;
            u32x2 v;
            v.x = pk(pb[0][j], pb[1][j]);
            v.y = pk(pb[2][j], pb[3][j]);
            *(u32x2*)(LB + r * ROWU32 + swz_col(r, 2 * bcq)) = v;
        }
        #pragma unroll
        for (int j = 0; j < 2; ++j) {
            const int r = 2 * adp0 + j;
            u32x2 v;
            v.x = pk(pa0[0][j], pa0[1][j]);
            v.y = pk(pa0[2][j], pa0[3][j]);
            *(u32x2*)(L + r * ROWU32 + swz_col(r, 2 * acq0)) = v;
        }
        if (hasA1) {
            #pragma unroll
            for (int j = 0; j < 2; ++j) {
                const int r = 2 * adp1 + j;
                u32x2 v;
                v.x = pk(pa1[0][j], pa1[1][j]);
                v.y = pk(pa1[2][j], pa1[3][j]);
                *(u32x2*)(L + r * ROWU32 + swz_col(r, 2 * acq1)) = v;
            }
        }
    };

    auto compute = [&](const unsigned* L) {
        const unsigned* LB = L + BOFF;
        bf16x8 af[3], bfr[4];
        #pragma unroll
        for (int m = 0; m < 3; ++m) {
            const int row = wr * 48 + m * 16 + lr;
            af[m] = *(const bf16x8*)(L + row * ROWU32 + ((lg ^ ((row >> 3) & 3)) << 2));
        }
        #pragma unroll
        for (int n = 0; n < 4; ++n) {
            const int row = wc * 64 + n * 16 + lr;
            bfr[n] = *(const bf16x8*)(LB + row * ROWU32 + ((lg ^ ((row >> 3) & 3)) << 2));
        }
        #pragma unroll
        for (int m = 0; m < 3; ++m)
            #pragma unroll
            for (int n = 0; n < 4; ++n)
                acc[m][n] = __builtin_amdgcn_mfma_f32_16x16x32_bf16(af[m], bfr[n], acc[m][n], 0, 0, 0);
    };

    // ---- prologue: stage K-step 0 ----
    {
        f32x4 pb[4]; f32x2 pa0[4], pa1[4];
        load_tiles(0, pb, pa0, pa1);
        store_tiles(&lds[0][0], pb, pa0, pa1);
    }
    __syncthreads();

    // ---- main pipeline ----
    int cur = 0;
    #pragma unroll 1
    for (int kk = 0; kk < NK - 1; ++kk) {
        f32x4 pb[4]; f32x2 pa0[4], pa1[4];
        load_tiles((kk + 1) * BK, pb, pa0, pa1);   // issue early (hidden under MFMA)
        compute(&lds[cur][0]);
        store_tiles(&lds[cur ^ 1][0], pb, pa0, pa1);
        __syncthreads();
        cur ^= 1;
    }
    compute(&lds[cur][0]);  // last K-step, no prefetch

    // ---- epilogue: C/D layout col=lane&15, row=(lane>>4)*4+reg ----
    float* outb = out + (size_t)b * (C_ * T_);
    #pragma unroll
    for (int m = 0; m < 3; ++m) {
        const int dbase = d0 + wr * 48 + m * 16 + 4 * lg;
        #pragma unroll
        for (int n = 0; n < 4; ++n) {
            const int t = t0 + wc * 64 + n * 16 + lr;
            #pragma unroll
            for (int rr = 0; rr < 4; ++rr) {
                const int d = dbase + rr;
                if (d < C_)
                    outb[(size_t)d * T_ + t] = acc[m][n][rr];
            }
        }
    }
}

extern "C" void kernel_launch(void* const* d_in, const int* in_sizes, int n_in,
                              void* d_out, int out_size, void* d_ws, size_t ws_size,
                              hipStream_t stream)
{
    const float* x        = (const float*)d_in[0];
    const int*   subjects = (const int*)d_in[1];
    const float* w        = (const float*)d_in[2];
    float* out            = (float*)d_out;

    dim3 grid(B_ * 24);  // 256 batches * (3 d-tiles * 8 t-tiles)
    dim3 block(256);
    hipLaunchKernelGGL(subj_layers_kernel, grid, block, 0, stream,
                       x, subjects, w, out);
}

// Round 4
// 180.260 us; speedup vs baseline: 1.6534x; 1.1684x over previous
//
#include <hip/hip_runtime.h>

// out[b,d,t] = sum_c x[b,c,t] * weights[subjects[b],c,d]
// B=256, C=270, T=1024, NSUB=200. fp32 in/out, bf16 MFMA internally.
// Depth-2 register prefetch + double-buffered LDS, 1 barrier per K-step,
// v_cvt_pk_bf16_f32 packing, XCD-chunked block swizzle (d-tiles adjacent).

#define C_    270
#define T_    1024
#define B_    256
#define NSUB_ 200

#define BM 96      // d-tile
#define BN 128     // t-tile
#define BK 32      // c-step
#define NK 9       // K padded 270 -> 288
#define ROWU32 20  // u32 per LDS row: 16 used (32 bf16) + 4 pad
#define BOFF (BM * ROWU32)
#define LDSU32 ((BM + BN) * ROWU32)

typedef __attribute__((ext_vector_type(8))) short bf16x8;
typedef __attribute__((ext_vector_type(4))) float f32x4;
typedef __attribute__((ext_vector_type(2))) float f32x2;
typedef __attribute__((ext_vector_type(2))) unsigned u32x2;

__device__ __forceinline__ unsigned pk(float lo, float hi) {
    // v_cvt_pk_bf16_f32: RNE, lo -> low 16 bits. No builtin on gfx950 (T12).
    unsigned r;
    asm("v_cvt_pk_bf16_f32 %0, %1, %2" : "=v"(r) : "v"(lo), "v"(hi));
    return r;
}

// 16-byte-block XOR swizzle on u32 columns: bits[3:2] ^= row bits[4:3].
__device__ __forceinline__ int swz_col(int row, int c2) {
    return (c2 & 3) | ((((c2 >> 2) ^ ((row >> 3) & 3)) & 3) << 2);
}

__global__ __launch_bounds__(256, 3)
void subj_layers_kernel(const float* __restrict__ x,
                        const int* __restrict__ subjects,
                        const float* __restrict__ w,
                        float* __restrict__ out)
{
    __shared__ unsigned lds[2][LDSU32];

    const int tid  = threadIdx.x;
    const int lane = tid & 63;
    const int wid  = tid >> 6;
    const int wr   = wid >> 1;   // wave d-row 0..1
    const int wc   = wid & 1;    // wave t-col 0..1
    const int lg   = lane >> 4;
    const int lr   = lane & 15;

    // Bijective XCD-chunk swizzle: 6144 blocks = 8 XCDs x 768. Round-robin
    // HW assignment (bid%8) -> chunk c gets consecutive logical ids. d-tile
    // fastest so the 3 blocks sharing an x-slice are same-XCD + adjacent.
    const int bid  = (blockIdx.x & 7) * 768 + (blockIdx.x >> 3);
    const int b    = bid / 24;
    const int rem  = bid % 24;
    const int d0   = (rem % 3) * BM;   // 0,96,192  (fastest)
    const int t0   = (rem / 3) * BN;   // 0..896

    int sub = subjects[b];
    sub = sub < 0 ? 0 : (sub >= NSUB_ ? NSUB_ - 1 : sub);
    const float* __restrict__ wsub = w + (size_t)sub * (C_ * C_);
    const float* __restrict__ xb   = x + (size_t)b * (C_ * T_);

    // ---- staging decomposition ----
    // B (x): item = (t-quad, c-quad): 4x float4 loads, 4x b64 writes
    const int btq = tid & 31;          // t-quad 0..31
    const int bcq = tid >> 5;          // c-quad 0..7
    const float* __restrict__ xbt = xb + (t0 + 4 * btq);
    // A (w): 384 items (48 d-pairs x 8 c-quads), 1.5/thread
    const int adp0 = tid % 48,         acq0 = tid / 48;
    const int adp1 = (256 + tid) % 48, acq1 = (256 + tid) / 48;
    const bool hasA1 = (tid < 128);
    const int dA0 = d0 + 2 * adp0;  const bool dA0ok = (dA0 + 1 < C_);
    const int dA1 = d0 + 2 * adp1;  const bool dA1ok = (dA1 + 1 < C_);

    f32x4 acc[3][4];
    #pragma unroll
    for (int m = 0; m < 3; ++m)
        #pragma unroll
        for (int n = 0; n < 4; ++n)
            acc[m][n] = (f32x4){0.f, 0.f, 0.f, 0.f};

    // full==true folds guards away at compile time (lambda is force-inlined)
    auto load_tiles = [&](int c0, bool full, f32x4 pb[4], f32x2 pa0[4], f32x2 pa1[4]) {
        #pragma unroll
        for (int e = 0; e < 4; ++e) {
            const int c = c0 + 4 * bcq + e;
            pb[e] = (full || c < C_) ? *(const f32x4*)(xbt + (size_t)c * T_)
                                     : (f32x4){0.f, 0.f, 0.f, 0.f};
        }
        #pragma unroll
        for (int e = 0; e < 4; ++e) {
            const int c = c0 + 4 * acq0 + e;
            pa0[e] = (dA0ok && (full || c < C_)) ? *(const f32x2*)(wsub + (size_t)c * C_ + dA0)
                                                 : (f32x2){0.f, 0.f};
        }
        #pragma unroll
        for (int e = 0; e < 4; ++e) {
            const int c = c0 + 4 * acq1 + e;
            pa1[e] = (hasA1 && dA1ok && (full || c < C_)) ? *(const f32x2*)(wsub + (size_t)c * C_ + dA1)
                                                          : (f32x2){0.f, 0.f};
        }
    };

    auto store_tiles = [&](unsigned* L, const f32x4 pb[4], const f32x2 pa0[4], const f32x2 pa1[4]) {
        unsigned* LB = L + BOFF;
        #pragma unroll
        for (int j = 0; j < 4; ++j) {
            const int r = 4 * btq + j;
            u32x2 v;
            v.x = pk(pb[0][j], pb[1][j]);
            v.y = pk(pb[2][j], pb[3][j]);
            *(u32x2*)(LB + r * ROWU32 + swz_col(r, 2 * bcq)) = v;
        }
        #pragma unroll
        for (int j = 0; j < 2; ++j) {
            const int r = 2 * adp0 + j;
            u32x2 v;
            v.x = pk(pa0[0][j], pa0[1][j]);
            v.y = pk(pa0[2][j], pa0[3][j]);
            *(u32x2*)(L + r * ROWU32 + swz_col(r, 2 * acq0)) = v;
        }
        if (hasA1) {
            #pragma unroll
            for (int j = 0; j < 2; ++j) {
                const int r = 2 * adp1 + j;
                u32x2 v;
                v.x = pk(pa1[0][j], pa1[1][j]);
                v.y = pk(pa1[2][j], pa1[3][j]);
                *(u32x2*)(L + r * ROWU32 + swz_col(r, 2 * acq1)) = v;
            }
        }
    };

    auto compute = [&](const unsigned* L) {
        const unsigned* LB = L + BOFF;
        bf16x8 af[3], bfr[4];
        #pragma unroll
        for (int m = 0; m < 3; ++m) {
            const int row = wr * 48 + m * 16 + lr;
            af[m] = *(const bf16x8*)(L + row * ROWU32 + ((lg ^ ((row >> 3) & 3)) << 2));
        }
        #pragma unroll
        for (int n = 0; n < 4; ++n) {
            const int row = wc * 64 + n * 16 + lr;
            bfr[n] = *(const bf16x8*)(LB + row * ROWU32 + ((lg ^ ((row >> 3) & 3)) << 2));
        }
        #pragma unroll
        for (int m = 0; m < 3; ++m)
            #pragma unroll
            for (int n = 0; n < 4; ++n)
                acc[m][n] = __builtin_amdgcn_mfma_f32_16x16x32_bf16(af[m], bfr[n], acc[m][n], 0, 0, 0);
    };

    // ---- two named prefetch slots (static indexing, rule #20) ----
    f32x4 pbA[4], pbB[4];
    f32x2 pa0A[4], pa1A[4], pa0B[4], pa1B[4];

    // prologue: tile0 -> lds0; tile1 in flight in slot B
    load_tiles(0, true, pbA, pa0A, pa1A);
    store_tiles(&lds[0][0], pbA, pa0A, pa1A);
    load_tiles(BK, true, pbB, pa0B, pa1B);
    __syncthreads();

    // main: tiles 0..5 computed here; loads t2..t7 all full
    #pragma unroll 1
    for (int kk = 0; kk < 6; kk += 2) {
        load_tiles((kk + 2) * BK, true, pbA, pa0A, pa1A);   // tile kk+2, 2 phases ahead
        compute(&lds[0][0]);                                 // tile kk
        store_tiles(&lds[1][0], pbB, pa0B, pa1B);            // tile kk+1 (arrived)
        __syncthreads();
        load_tiles((kk + 3) * BK, true, pbB, pa0B, pa1B);   // tile kk+3
        compute(&lds[1][0]);                                 // tile kk+1
        store_tiles(&lds[0][0], pbA, pa0A, pa1A);            // tile kk+2
        __syncthreads();
    }
    // peeled tail: tiles 6,7,8 (tile 8 partial -> guarded load)
    load_tiles(8 * BK, false, pbA, pa0A, pa1A);  // tile 8, c-guards live
    compute(&lds[0][0]);                          // tile 6
    store_tiles(&lds[1][0], pbB, pa0B, pa1B);     // tile 7
    __syncthreads();
    compute(&lds[1][0]);                          // tile 7
    store_tiles(&lds[0][0], pbA, pa0A, pa1A);     // tile 8
    __syncthreads();
    compute(&lds[0][0]);                          // tile 8

    // ---- epilogue: C/D layout col=lane&15, row=(lane>>4)*4+reg ----
    float* outb = out + (size_t)b * (C_ * T_);
    #pragma unroll
    for (int m = 0; m < 3; ++m) {
        const int dbase = d0 + wr * 48 + m * 16 + 4 * lg;
        #pragma unroll
        for (int n = 0; n < 4; ++n) {
            const int t = t0 + wc * 64 + n * 16 + lr;
            #pragma unroll
            for (int rr = 0; rr < 4; ++rr) {
                const int d = dbase + rr;
                if (d < C_)
                    outb[(size_t)d * T_ + t] = acc[m][n][rr];
            }
        }
    }
}

extern "C" void kernel_launch(void* const* d_in, const int* in_sizes, int n_in,
                              void* d_out, int out_size, void* d_ws, size_t ws_size,
                              hipStream_t stream)
{
    const float* x        = (const float*)d_in[0];
    const int*   subjects = (const int*)d_in[1];
    const float* w        = (const float*)d_in[2];
    float* out            = (float*)d_out;

    dim3 grid(B_ * 24);  // 256 batches * (3 d-tiles * 8 t-tiles)
    dim3 block(256);
    hipLaunchKernelGGL(subj_layers_kernel, grid, block, 0, stream,
                       x, subjects, w, out);
}